// Round 20
// baseline (364.148 us; speedup 1.0000x reference)
//
#include <hip/hip_runtime.h>
#include <math.h>

#define INCH 128
#define DH 64     // d*h
#define H  32
#define D  2
#define LAYERS 4
#define OUTC 32

typedef __fp16 half2h __attribute__((ext_vector_type(2)));
typedef __fp16 half4 __attribute__((ext_vector_type(4)));
typedef __fp16 half8 __attribute__((ext_vector_type(8)));
typedef float  f32x4 __attribute__((ext_vector_type(4)));

#define TANH_K 2.885390081777927f   // 2*log2(e)

__device__ __forceinline__ float eluf(float v) { return v > 0.f ? v : expm1f(v); }

// fast tanh: (e^2x - 1) * rcp(e^2x + 1)
__device__ __forceinline__ float ftanh(float x) {
    float xc = fminf(9.0f, fmaxf(-9.0f, x));
    float e2 = __builtin_amdgcn_exp2f(xc * TANH_K);
    return (e2 - 1.0f) * __builtin_amdgcn_rcpf(e2 + 1.0f);
}
// tanh(a)*tanh(b) with a single rcp
__device__ __forceinline__ float ftanh_pair(float a, float b) {
    float ac = fminf(9.0f, fmaxf(-9.0f, a));
    float bc = fminf(9.0f, fmaxf(-9.0f, b));
    float ea = __builtin_amdgcn_exp2f(ac * TANH_K);
    float eb = __builtin_amdgcn_exp2f(bc * TANH_K);
    return (ea - 1.0f) * (eb - 1.0f) * __builtin_amdgcn_rcpf((ea + 1.0f) * (eb + 1.0f));
}

// ---------------- fused: one-time weight prep + degree histogram ----------------
__global__ void k_prep_hist(const float* __restrict__ W1, const float* __restrict__ W2,
                            const float* __restrict__ Wleft, const float* __restrict__ Wright,
                            __fp16* __restrict__ W1h, __fp16* __restrict__ W2h,
                            __fp16* __restrict__ Mlrh,
                            const int* __restrict__ src, int* __restrict__ deg,
                            int Bp, int E) {
    if (blockIdx.x >= Bp) {
        int e = (blockIdx.x - Bp) * 256 + threadIdx.x;
        if (e < E) atomicAdd(&deg[src[e]], 1);
        return;
    }
    int idx = blockIdx.x * 256 + threadIdx.x;
    if (idx < DH * INCH) {
        W1h[idx] = (__fp16)W1[idx];
    } else if (idx < DH * INCH + OUTC * DH) {
        int i = idx - DH * INCH;
        W2h[i] = (__fp16)W2[i];
    } else if (idx < DH * INCH + OUTC * DH + LAYERS * DH * DH) {
        int i = idx - DH * INCH - OUTC * DH;
        int l = i >> 12;
        int r = i & 4095;
        int row = r >> 6;         // sp*32 + c
        int col = r & 63;         // s*32 + cp
        int sp = row >> 5, c = row & 31;
        int s  = col >> 5, cp = col & 31;
        Mlrh[i] = (__fp16)(Wleft[l * 4 + sp * 2 + s] * Wright[l * 1024 + c * 32 + cp]);
    }
}

__global__ void k_bsum(const int* __restrict__ deg, int* __restrict__ bsum, int N) {
    int b = blockIdx.x, t = threadIdx.x;
    int lane = t & 63, wid = t >> 6;
    int base = b * 1024 + t * 4;
    int s = 0;
    #pragma unroll
    for (int i = 0; i < 4; ++i) {
        int idx = base + i;
        if (idx < N) s += deg[idx];
    }
    #pragma unroll
    for (int ofs = 32; ofs; ofs >>= 1) s += __shfl_xor(s, ofs);
    __shared__ int ws[4];
    if (lane == 0) ws[wid] = s;
    __syncthreads();
    if (t == 0) bsum[b] = ws[0] + ws[1] + ws[2] + ws[3];
}

__global__ void k_scan_small(int* __restrict__ bsum, int B) {
    int lane = threadIdx.x;
    int carry = 0;
    for (int base = 0; base < B; base += 64) {
        int i = base + lane;
        int v = (i < B) ? bsum[i] : 0;
        int incl = v;
        #pragma unroll
        for (int ofs = 1; ofs < 64; ofs <<= 1) {
            int tt = __shfl_up(incl, ofs);
            if (lane >= ofs) incl += tt;
        }
        if (i < B) bsum[i] = carry + incl - v;
        carry += __shfl(incl, 63);
    }
}

// final: local exclusive scan + block offset; also writes cur = rowptr
__global__ void k_scan_final(const int* __restrict__ deg, const int* __restrict__ bsum,
                             int* __restrict__ rowptr, int* __restrict__ cur, int N) {
    int b = blockIdx.x, t = threadIdx.x;
    int lane = t & 63, wid = t >> 6;
    int base = b * 1024 + t * 4;
    int v[4];
    int s = 0;
    #pragma unroll
    for (int i = 0; i < 4; ++i) {
        int idx = base + i;
        v[i] = (idx < N) ? deg[idx] : 0;
        s += v[i];
    }
    int incl = s;
    #pragma unroll
    for (int ofs = 1; ofs < 64; ofs <<= 1) {
        int tt = __shfl_up(incl, ofs);
        if (lane >= ofs) incl += tt;
    }
    __shared__ int ws[4];
    if (lane == 63) ws[wid] = incl;
    __syncthreads();
    int woff = 0;
    for (int k = 0; k < wid; ++k) woff += ws[k];
    int excl = bsum[b] + woff + incl - s;
    #pragma unroll
    for (int i = 0; i < 4; ++i) {
        int idx = base + i;
        if (idx < N) { rowptr[idx] = excl; cur[idx] = excl; }
        excl += v[i];
        if (idx == N - 1) rowptr[N] = excl;
    }
}

// ---------------- fused: CSR scatter (latency-bound) + mlp1/P0Q0 (MFMA-bound) ----------------
__global__ __launch_bounds__(256) void k_scatter_mlp1(
        const int* __restrict__ src, const int* __restrict__ dst,
        int* __restrict__ cur, unsigned short* __restrict__ csr_dst, int E,
        const float* __restrict__ xin, const __fp16* __restrict__ W1h,
        const float* __restrict__ b1, const float* __restrict__ Ws0,
        float* __restrict__ X, __fp16* __restrict__ NDh, int Bs, int N) {
    __shared__ float xs[16 * INCH];          // 8 KB
    __shared__ __fp16 wsh[DH * 132];         // 16.9 KB
    __shared__ float xout[16 * DH];          // 4 KB
    if (blockIdx.x < Bs) {
        int e = blockIdx.x * 256 + threadIdx.x;
        if (e < E) {
            int pos = atomicAdd(&cur[src[e]], 1);
            csr_dst[pos] = (unsigned short)dst[e];
        }
        return;
    }
    int t = threadIdx.x;
    int node0 = (blockIdx.x - Bs) * 16;
    for (int i = t; i < 16 * INCH / 4; i += 256) {
        int r = i >> 5, c = (i & 31) * 4;
        int node = node0 + r;
        f32x4 v = (node < N) ? __builtin_nontemporal_load((const f32x4*)(xin + (size_t)node * INCH + c))
                             : (f32x4){0.f, 0.f, 0.f, 0.f};
        *(f32x4*)&xs[r * INCH + c] = v;
    }
    for (int i = t; i < DH * INCH / 4; i += 256) {
        int r = i >> 5, c = (i & 31) * 4;
        *(uint2*)&wsh[r * 132 + c] = ((const uint2*)W1h)[i];
    }
    __syncthreads();
    int w = t >> 6, lane = t & 63;
    int oc0 = w * 16;
    int rr = lane & 15, g = lane >> 4;
    f32x4 acc = {0.f, 0.f, 0.f, 0.f};
    #pragma unroll
    for (int ks = 0; ks < INCH / 16; ++ks) {
        f32x4 xv = *(const f32x4*)&xs[rr * INCH + ks * 16 + g * 4];
        half4 af = {(__fp16)xv.x, (__fp16)xv.y, (__fp16)xv.z, (__fp16)xv.w};
        half4 bf = *(const half4*)&wsh[(oc0 + rr) * 132 + ks * 16 + g * 4];
        acc = __builtin_amdgcn_mfma_f32_16x16x16f16(af, bf, acc, 0, 0, 0);
    }
    int oc = oc0 + rr;
    float bb = b1[oc];
    #pragma unroll
    for (int r = 0; r < 4; ++r) {
        int node = node0 + g * 4 + r;
        float v = eluf(acc[r] + bb);
        xout[(g * 4 + r) * DH + oc] = v;
        if (node < N) X[(size_t)node * DH + oc] = v;
    }
    __syncthreads();
    float wsa = Ws0[lane];
    float wsb = Ws0[64 + lane];
    float wsc = Ws0[128 + lane];
    float wsd = Ws0[192 + lane];
    #pragma unroll
    for (int j = 0; j < 4; ++j) {
        int nl = w * 4 + j;
        int node = node0 + nl;
        float x = xout[nl * DH + lane];
        float p0 = x * wsa, q0 = x * wsb, p1 = x * wsc, q1 = x * wsd;
        #pragma unroll
        for (int ofs = 32; ofs; ofs >>= 1) {
            p0 += __shfl_xor(p0, ofs);
            q0 += __shfl_xor(q0, ofs);
            p1 += __shfl_xor(p1, ofs);
            q1 += __shfl_xor(q1, ofs);
        }
        if (lane == 0 && node < N) {
            half4 pq = {(__fp16)p0, (__fp16)p1, (__fp16)q0, (__fp16)q1};
            *(half4*)(NDh + (size_t)node * 8) = pq;
        }
    }
}

// merged: blocks [0, Bdg) do degree pass; blocks [Bdg, Bdg+Blr) do XW GEMM
// XW layout: XWI[node*64 + m*8 + st*4 + j]  (quad-major, stalk-interleaved)
__global__ __launch_bounds__(256) void k_dglr(__fp16* __restrict__ NDh,
                                              const int* __restrict__ rowptr,
                                              const unsigned short* __restrict__ csr_dst,
                                              const float* __restrict__ X,
                                              const __fp16* __restrict__ Mlrh_l,
                                              __fp16* __restrict__ XWI,
                                              int Bdg, int N) {
    __shared__ float xs[16 * DH];
    __shared__ __fp16 mlh[DH * 68];
    if (blockIdx.x < Bdg) {
        int lane = threadIdx.x & 63;
        int widl = threadIdx.x >> 6;
        int nn = lane >> 4, sub = lane & 15;
        int node = blockIdx.x * 16 + widl * 4 + nn;
        if (node >= N) return;
        half4 pqu = *(const half4*)(NDh + (size_t)node * 8);
        float pu0 = (float)pqu[0], pu1 = (float)pqu[1];
        int pos = rowptr[node], end = rowptr[node + 1];
        float sx = 0.f, sy = 0.f;
        for (int i = pos + sub; i < end; i += 16) {
            int v = (int)__builtin_nontemporal_load(csr_dst + i);
            half4 pqv = *(const half4*)(NDh + (size_t)v * 8);
            float fx = ftanh(pu0 + (float)pqv[2]);
            float fy = ftanh(pu1 + (float)pqv[3]);
            sx += fx * fx;
            sy += fy * fy;
        }
        #pragma unroll
        for (int ofs = 8; ofs; ofs >>= 1) {
            sx += __shfl_xor(sx, ofs);
            sy += __shfl_xor(sy, ofs);
        }
        if (sub == 0) {
            float i0 = 1.f / (sx + 1.f), i1 = 1.f / (sy + 1.f);
            half4 gi = {(__fp16)sqrtf(i0), (__fp16)sqrtf(i1), (__fp16)(sx * i0), (__fp16)(sy * i1)};
            *(half4*)(NDh + (size_t)node * 8 + 4) = gi;
        }
        return;
    }
    int t = threadIdx.x;
    int node0 = (blockIdx.x - Bdg) * 16;
    for (int i = t; i < 16 * DH / 4; i += 256) {
        int r = i >> 4, c = (i & 15) * 4;
        int node = node0 + r;
        f32x4 v = (node < N) ? __builtin_nontemporal_load((const f32x4*)(X + (size_t)node * DH + c))
                             : (f32x4){0.f, 0.f, 0.f, 0.f};
        *(f32x4*)&xs[r * DH + c] = v;
    }
    for (int i = t; i < DH * DH / 4; i += 256) {
        int r = i >> 4, c = (i & 15) * 4;
        *(uint2*)&mlh[r * 68 + c] = ((const uint2*)Mlrh_l)[i];
    }
    __syncthreads();
    int w = t >> 6, lane = t & 63;
    int oc0 = w * 16;
    int rr = lane & 15, g = lane >> 4;
    f32x4 acc = {0.f, 0.f, 0.f, 0.f};
    #pragma unroll
    for (int ks = 0; ks < DH / 16; ++ks) {
        f32x4 xv = *(const f32x4*)&xs[rr * DH + ks * 16 + g * 4];
        half4 af = {(__fp16)xv.x, (__fp16)xv.y, (__fp16)xv.z, (__fp16)xv.w};
        half4 bf = *(const half4*)&mlh[(oc0 + rr) * 68 + ks * 16 + g * 4];
        acc = __builtin_amdgcn_mfma_f32_16x16x16f16(af, bf, acc, 0, 0, 0);
    }
    int oc = oc0 + rr;
    int sp = oc >> 5, c = oc & 31;
    int cidx = (c >> 2) * 8 + sp * 4 + (c & 3);
    #pragma unroll
    for (int r = 0; r < 4; ++r) {
        int node = node0 + g * 4 + r;
        if (node < N) XWI[(size_t)node * 64 + cidx] = (__fp16)acc[r];
    }
}

__global__ __launch_bounds__(256) void k_out(const float* __restrict__ X,
                                             const __fp16* __restrict__ W2h,
                                             const float* __restrict__ b2,
                                             float* __restrict__ out, int N) {
    __shared__ float xs[32 * DH];
    __shared__ __fp16 w2s[OUTC * 68];
    int t = threadIdx.x;
    int node0 = blockIdx.x * 32;
    for (int i = t; i < 32 * DH / 4; i += 256) {
        int r = i >> 4, c = (i & 15) * 4;
        int node = node0 + r;
        f32x4 v = (node < N) ? __builtin_nontemporal_load((const f32x4*)(X + (size_t)node * DH + c))
                             : (f32x4){0.f, 0.f, 0.f, 0.f};
        *(f32x4*)&xs[r * DH + c] = v;
    }
    for (int i = t; i < OUTC * DH / 4; i += 256) {
        int r = i >> 4, c = (i & 15) * 4;
        *(uint2*)&w2s[r * 68 + c] = ((const uint2*)W2h)[i];
    }
    __syncthreads();
    int w = t >> 6, lane = t & 63;
    int nt = w >> 1;
    int oc0 = (w & 1) * 16;
    int rr = lane & 15, g = lane >> 4;
    f32x4 acc = {0.f, 0.f, 0.f, 0.f};
    #pragma unroll
    for (int ks = 0; ks < DH / 16; ++ks) {
        f32x4 xv = *(const f32x4*)&xs[(nt * 16 + rr) * DH + ks * 16 + g * 4];
        half4 af = {(__fp16)xv.x, (__fp16)xv.y, (__fp16)xv.z, (__fp16)xv.w};
        half4 bf = *(const half4*)&w2s[(oc0 + rr) * 68 + ks * 16 + g * 4];
        acc = __builtin_amdgcn_mfma_f32_16x16x16f16(af, bf, acc, 0, 0, 0);
    }
    int oc = oc0 + rr;
    float bb = b2[oc];
    #pragma unroll
    for (int r = 0; r < 4; ++r) {
        int node = node0 + nt * 16 + g * 4 + r;
        if (node < N) out[(size_t)node * OUTC + oc] = acc[r] + bb;
    }
}

// ---------------- spmm + finalize + next-layer P/Q ----------------
__global__ void k_spmm_fin_pq(const __fp16* __restrict__ XWI,
                              const __fp16* __restrict__ NDh, const int* __restrict__ rowptr,
                              const unsigned short* __restrict__ csr_dst,
                              const float* __restrict__ eps_l, const float* __restrict__ Wsn,
                              float* __restrict__ X, __fp16* __restrict__ NDhn, int N) {
    int wid = (blockIdx.x * blockDim.x + threadIdx.x) >> 6;
    int lane = threadIdx.x & 63;
    if (wid >= N) return;
    int q = lane >> 3;        // edge slot 0..7
    int m = lane & 7;         // channel quad within stalk
    half8 ndu = *(const half8*)(NDh + (size_t)wid * 8);
    float pu0 = (float)ndu[0], pu1 = (float)ndu[1];
    float qu0 = (float)ndu[2], qu1 = (float)ndu[3];
    float dinv0 = (float)ndu[4], dinv1 = (float)ndu[5];
    int pos = rowptr[wid], end = rowptr[wid + 1];

    float a0x = 0.f, a0y = 0.f, a0z = 0.f, a0w = 0.f;
    float a1x = 0.f, a1y = 0.f, a1z = 0.f, a1w = 0.f;

    for (int chunk = pos; chunk < end; chunk += 64) {
        int myidx = chunk + lane;
        int dmy = 0;
        unsigned wpkmy = 0;
        if (myidx < end) {
            dmy = (int)__builtin_nontemporal_load(csr_dst + myidx);
            half8 ndd = *(const half8*)(NDh + (size_t)dmy * 8);
            float prod0 = ftanh_pair(pu0 + (float)ndd[2], (float)ndd[0] + qu0);
            float prod1 = ftanh_pair(pu1 + (float)ndd[3], (float)ndd[1] + qu1);
            float w0 = -prod0 * dinv0 * (float)ndd[4];
            float w1 = -prod1 * dinv1 * (float)ndd[5];
            half2h wp = {(__fp16)w0, (__fp16)w1};
            __builtin_memcpy(&wpkmy, &wp, 4);
        }
        int lim = end - chunk; if (lim > 64) lim = 64;
        for (int b = 0; b < lim; b += 8) {
            int sl = b + q;
            int d        = __shfl(dmy, sl);
            unsigned wpk = __shfl((int)wpkmy, sl);   // 0 for sl >= row length
            half2h wp;
            __builtin_memcpy(&wp, &wpk, 4);
            float w0e = (float)wp.x, w1e = (float)wp.y;
            half8 g = *(const half8*)(XWI + (size_t)d * 64 + m * 8);
            a0x += w0e * (float)g[0]; a0y += w0e * (float)g[1];
            a0z += w0e * (float)g[2]; a0w += w0e * (float)g[3];
            a1x += w1e * (float)g[4]; a1y += w1e * (float)g[5];
            a1z += w1e * (float)g[6]; a1w += w1e * (float)g[7];
        }
    }
    #pragma unroll
    for (int ofs = 8; ofs <= 32; ofs <<= 1) {
        a0x += __shfl_xor(a0x, ofs); a0y += __shfl_xor(a0y, ofs);
        a0z += __shfl_xor(a0z, ofs); a0w += __shfl_xor(a0w, ofs);
        a1x += __shfl_xor(a1x, ofs); a1y += __shfl_xor(a1y, ofs);
        a1z += __shfl_xor(a1z, ofs); a1w += __shfl_xor(a1w, ofs);
    }
    if (q == 0) {
        float diag0 = (float)ndu[6];
        float diag1 = (float)ndu[7];
        half8 xw = *(const half8*)(XWI + (size_t)wid * 64 + m * 8);
        size_t b0 = (size_t)wid * DH + m * 4;
        size_t b1 = b0 + 32;
        float coeff0 = 1.f + ftanh(eps_l[0]);
        float coeff1 = 1.f + ftanh(eps_l[1]);
        f32x4 xo0 = __builtin_nontemporal_load((const f32x4*)(X + b0));
        f32x4 xo1 = __builtin_nontemporal_load((const f32x4*)(X + b1));
        f32x4 xn0, xn1;
        xn0.x = coeff0 * xo0.x - eluf(diag0 * (float)xw[0] + a0x);
        xn0.y = coeff0 * xo0.y - eluf(diag0 * (float)xw[1] + a0y);
        xn0.z = coeff0 * xo0.z - eluf(diag0 * (float)xw[2] + a0z);
        xn0.w = coeff0 * xo0.w - eluf(diag0 * (float)xw[3] + a0w);
        xn1.x = coeff1 * xo1.x - eluf(diag1 * (float)xw[4] + a1x);
        xn1.y = coeff1 * xo1.y - eluf(diag1 * (float)xw[5] + a1y);
        xn1.z = coeff1 * xo1.z - eluf(diag1 * (float)xw[6] + a1z);
        xn1.w = coeff1 * xo1.w - eluf(diag1 * (float)xw[7] + a1w);
        __builtin_nontemporal_store(xn0, (f32x4*)(X + b0));
        __builtin_nontemporal_store(xn1, (f32x4*)(X + b1));
        if (Wsn) {
            f32x4 wa0 = *(const f32x4*)(Wsn + m * 4);
            f32x4 wa1 = *(const f32x4*)(Wsn + 32 + m * 4);
            f32x4 wb0 = *(const f32x4*)(Wsn + 64 + m * 4);
            f32x4 wb1 = *(const f32x4*)(Wsn + 96 + m * 4);
            f32x4 wc0 = *(const f32x4*)(Wsn + 128 + m * 4);
            f32x4 wc1 = *(const f32x4*)(Wsn + 160 + m * 4);
            f32x4 wd0 = *(const f32x4*)(Wsn + 192 + m * 4);
            f32x4 wd1 = *(const f32x4*)(Wsn + 224 + m * 4);
            float p0 = xn0.x * wa0.x + xn0.y * wa0.y + xn0.z * wa0.z + xn0.w * wa0.w
                     + xn1.x * wa1.x + xn1.y * wa1.y + xn1.z * wa1.z + xn1.w * wa1.w;
            float q0 = xn0.x * wb0.x + xn0.y * wb0.y + xn0.z * wb0.z + xn0.w * wb0.w
                     + xn1.x * wb1.x + xn1.y * wb1.y + xn1.z * wb1.z + xn1.w * wb1.w;
            float p1 = xn0.x * wc0.x + xn0.y * wc0.y + xn0.z * wc0.z + xn0.w * wc0.w
                     + xn1.x * wc1.x + xn1.y * wc1.y + xn1.z * wc1.z + xn1.w * wc1.w;
            float q1 = xn0.x * wd0.x + xn0.y * wd0.y + xn0.z * wd0.z + xn0.w * wd0.w
                     + xn1.x * wd1.x + xn1.y * wd1.y + xn1.z * wd1.z + xn1.w * wd1.w;
            #pragma unroll
            for (int ofs = 1; ofs < 8; ofs <<= 1) {
                p0 += __shfl_xor(p0, ofs);
                q0 += __shfl_xor(q0, ofs);
                p1 += __shfl_xor(p1, ofs);
                q1 += __shfl_xor(q1, ofs);
            }
            if (m == 0) {
                half4 pq = {(__fp16)p0, (__fp16)p1, (__fp16)q0, (__fp16)q1};
                *(half4*)(NDhn + (size_t)wid * 8) = pq;
            }
        }
    }
}

extern "C" void kernel_launch(void* const* d_in, const int* in_sizes, int n_in,
                              void* d_out, int out_size, void* d_ws, size_t ws_size,
                              hipStream_t stream) {
    const float* xin    = (const float*)d_in[0];
    const int*   ei     = (const int*)d_in[1];
    const float* W1     = (const float*)d_in[2];
    const float* b1     = (const float*)d_in[3];
    const float* Wsheaf = (const float*)d_in[4];
    const float* Wleft  = (const float*)d_in[5];
    const float* Wright = (const float*)d_in[6];
    const float* eps    = (const float*)d_in[7];
    const float* W2     = (const float*)d_in[8];
    const float* b2     = (const float*)d_in[9];
    float* out = (float*)d_out;

    int N = in_sizes[0] / INCH;
    int E = in_sizes[1] / 2;
    const int* src = ei;
    const int* dst = ei + E;

    size_t off = 0;
    auto alloc = [&](size_t nbytes) {
        char* p = (char*)d_ws + off;
        off += (nbytes + 255) & ~(size_t)255;
        return p;
    };
    float*          X       = (float*)alloc((size_t)N * DH * 4);
    __fp16*         XWI     = (__fp16*)alloc((size_t)N * DH * 2);
    __fp16*         NDha    = (__fp16*)alloc((size_t)N * 16);
    __fp16*         NDhb    = (__fp16*)alloc((size_t)N * 16);
    int*            deg     = (int*)alloc((size_t)N * 4);
    int*            rowptr  = (int*)alloc(((size_t)N + 1) * 4);
    int*            cur     = (int*)alloc((size_t)N * 4);
    unsigned short* csr_dst = (unsigned short*)alloc((size_t)E * 2);
    int*            bsum    = (int*)alloc(4096);
    __fp16*         W1h     = (__fp16*)alloc((size_t)DH * INCH * 2);
    __fp16*         W2h     = (__fp16*)alloc((size_t)OUTC * DH * 2);
    __fp16*         Mlrh    = (__fp16*)alloc((size_t)LAYERS * DH * DH * 2);

    int B = (N + 1023) / 1024;

    int prep_total = DH * INCH + OUTC * DH + LAYERS * DH * DH;
    int Bp = (prep_total + 255) / 256;
    int Bh = (E + 255) / 256;
    hipMemsetAsync(deg, 0, (size_t)N * sizeof(int), stream);
    k_prep_hist<<<Bp + Bh, 256, 0, stream>>>(W1, W2, Wleft, Wright, W1h, W2h, Mlrh,
                                             src, deg, Bp, E);
    k_bsum<<<B, 256, 0, stream>>>(deg, bsum, N);
    k_scan_small<<<1, 64, 0, stream>>>(bsum, B);
    k_scan_final<<<B, 256, 0, stream>>>(deg, bsum, rowptr, cur, N);

    int Bs = (E + 255) / 256;
    int Bm = (N + 15) / 16;
    k_scatter_mlp1<<<Bs + Bm, 256, 0, stream>>>(src, dst, cur, csr_dst, E,
                                                xin, W1h, b1, Wsheaf, X, NDha, Bs, N);

    __fp16* NDcur = NDha;
    __fp16* NDnext = NDhb;
    int Bdg = (N + 15) / 16;
    int Blr = (N + 15) / 16;
    for (int l = 0; l < LAYERS; ++l) {
        k_dglr<<<Bdg + Blr, 256, 0, stream>>>(NDcur, rowptr, csr_dst, X,
                                              Mlrh + (size_t)l * DH * DH, XWI, Bdg, N);
        const float* Wsn = (l + 1 < LAYERS) ? (Wsheaf + (l + 1) * 2 * INCH) : nullptr;
        k_spmm_fin_pq<<<(N + 3) / 4, 256, 0, stream>>>(XWI, NDcur, rowptr, csr_dst,
                                                       eps + l * 2, Wsn, X, NDnext, N);
        __fp16* tmp = NDcur; NDcur = NDnext; NDnext = tmp;
    }

    k_out<<<(N + 31) / 32, 256, 0, stream>>>(X, W2h, b2, out, N);
}

// Round 21
// 354.666 us; speedup vs baseline: 1.0267x; 1.0267x over previous
//
#include <hip/hip_runtime.h>
#include <math.h>

#define INCH 128
#define DH 64     // d*h
#define H  32
#define D  2
#define LAYERS 4
#define OUTC 32

typedef __fp16 half2h __attribute__((ext_vector_type(2)));
typedef __fp16 half4 __attribute__((ext_vector_type(4)));
typedef __fp16 half8 __attribute__((ext_vector_type(8)));
typedef float  f32x4 __attribute__((ext_vector_type(4)));

#define TANH_K 2.885390081777927f   // 2*log2(e)

__device__ __forceinline__ float eluf(float v) { return v > 0.f ? v : expm1f(v); }

// fast tanh: (e^2x - 1) * rcp(e^2x + 1)
__device__ __forceinline__ float ftanh(float x) {
    float xc = fminf(9.0f, fmaxf(-9.0f, x));
    float e2 = __builtin_amdgcn_exp2f(xc * TANH_K);
    return (e2 - 1.0f) * __builtin_amdgcn_rcpf(e2 + 1.0f);
}
// tanh(a)*tanh(b) with a single rcp
__device__ __forceinline__ float ftanh_pair(float a, float b) {
    float ac = fminf(9.0f, fmaxf(-9.0f, a));
    float bc = fminf(9.0f, fmaxf(-9.0f, b));
    float ea = __builtin_amdgcn_exp2f(ac * TANH_K);
    float eb = __builtin_amdgcn_exp2f(bc * TANH_K);
    return (ea - 1.0f) * (eb - 1.0f) * __builtin_amdgcn_rcpf((ea + 1.0f) * (eb + 1.0f));
}

// ---------------- fused: one-time weight prep + degree histogram ----------------
__global__ void k_prep_hist(const float* __restrict__ W1, const float* __restrict__ W2,
                            const float* __restrict__ Wleft, const float* __restrict__ Wright,
                            __fp16* __restrict__ W1h, __fp16* __restrict__ W2h,
                            __fp16* __restrict__ Mlrh,
                            const int* __restrict__ src, int* __restrict__ deg,
                            int Bp, int E) {
    if (blockIdx.x >= Bp) {
        int e = (blockIdx.x - Bp) * 256 + threadIdx.x;
        if (e < E) atomicAdd(&deg[src[e]], 1);
        return;
    }
    int idx = blockIdx.x * 256 + threadIdx.x;
    if (idx < DH * INCH) {
        W1h[idx] = (__fp16)W1[idx];
    } else if (idx < DH * INCH + OUTC * DH) {
        int i = idx - DH * INCH;
        W2h[i] = (__fp16)W2[i];
    } else if (idx < DH * INCH + OUTC * DH + LAYERS * DH * DH) {
        int i = idx - DH * INCH - OUTC * DH;
        int l = i >> 12;
        int r = i & 4095;
        int row = r >> 6;         // sp*32 + c
        int col = r & 63;         // s*32 + cp
        int sp = row >> 5, c = row & 31;
        int s  = col >> 5, cp = col & 31;
        Mlrh[i] = (__fp16)(Wleft[l * 4 + sp * 2 + s] * Wright[l * 1024 + c * 32 + cp]);
    }
}

__global__ void k_bsum(const int* __restrict__ deg, int* __restrict__ bsum, int N) {
    int b = blockIdx.x, t = threadIdx.x;
    int lane = t & 63, wid = t >> 6;
    int base = b * 1024 + t * 4;
    int s = 0;
    #pragma unroll
    for (int i = 0; i < 4; ++i) {
        int idx = base + i;
        if (idx < N) s += deg[idx];
    }
    #pragma unroll
    for (int ofs = 32; ofs; ofs >>= 1) s += __shfl_xor(s, ofs);
    __shared__ int ws[4];
    if (lane == 0) ws[wid] = s;
    __syncthreads();
    if (t == 0) bsum[b] = ws[0] + ws[1] + ws[2] + ws[3];
}

__global__ void k_scan_small(int* __restrict__ bsum, int B) {
    int lane = threadIdx.x;
    int carry = 0;
    for (int base = 0; base < B; base += 64) {
        int i = base + lane;
        int v = (i < B) ? bsum[i] : 0;
        int incl = v;
        #pragma unroll
        for (int ofs = 1; ofs < 64; ofs <<= 1) {
            int tt = __shfl_up(incl, ofs);
            if (lane >= ofs) incl += tt;
        }
        if (i < B) bsum[i] = carry + incl - v;
        carry += __shfl(incl, 63);
    }
}

// final: local exclusive scan + block offset; also writes cur = rowptr
__global__ void k_scan_final(const int* __restrict__ deg, const int* __restrict__ bsum,
                             int* __restrict__ rowptr, int* __restrict__ cur, int N) {
    int b = blockIdx.x, t = threadIdx.x;
    int lane = t & 63, wid = t >> 6;
    int base = b * 1024 + t * 4;
    int v[4];
    int s = 0;
    #pragma unroll
    for (int i = 0; i < 4; ++i) {
        int idx = base + i;
        v[i] = (idx < N) ? deg[idx] : 0;
        s += v[i];
    }
    int incl = s;
    #pragma unroll
    for (int ofs = 1; ofs < 64; ofs <<= 1) {
        int tt = __shfl_up(incl, ofs);
        if (lane >= ofs) incl += tt;
    }
    __shared__ int ws[4];
    if (lane == 63) ws[wid] = incl;
    __syncthreads();
    int woff = 0;
    for (int k = 0; k < wid; ++k) woff += ws[k];
    int excl = bsum[b] + woff + incl - s;
    #pragma unroll
    for (int i = 0; i < 4; ++i) {
        int idx = base + i;
        if (idx < N) { rowptr[idx] = excl; cur[idx] = excl; }
        excl += v[i];
        if (idx == N - 1) rowptr[N] = excl;
    }
}

// ---------------- fused: CSR scatter (latency-bound) + mlp1/P0Q0 (MFMA-bound) ----------------
__global__ __launch_bounds__(256) void k_scatter_mlp1(
        const int* __restrict__ src, const int* __restrict__ dst,
        int* __restrict__ cur, unsigned short* __restrict__ csr_dst, int E,
        const float* __restrict__ xin, const __fp16* __restrict__ W1h,
        const float* __restrict__ b1, const float* __restrict__ Ws0,
        float* __restrict__ X, __fp16* __restrict__ NDh, int Bs, int N) {
    __shared__ float xs[16 * 132];           // padded rows: +4 floats kills 16-way MFMA-read conflicts
    __shared__ __fp16 wsh[DH * 132];
    __shared__ float xout[16 * 68];          // padded
    if (blockIdx.x < Bs) {
        int e = blockIdx.x * 256 + threadIdx.x;
        if (e < E) {
            int pos = atomicAdd(&cur[src[e]], 1);
            csr_dst[pos] = (unsigned short)dst[e];
        }
        return;
    }
    int t = threadIdx.x;
    int node0 = (blockIdx.x - Bs) * 16;
    for (int i = t; i < 16 * INCH / 4; i += 256) {
        int r = i >> 5, c = (i & 31) * 4;
        int node = node0 + r;
        f32x4 v = (node < N) ? __builtin_nontemporal_load((const f32x4*)(xin + (size_t)node * INCH + c))
                             : (f32x4){0.f, 0.f, 0.f, 0.f};
        *(f32x4*)&xs[r * 132 + c] = v;
    }
    for (int i = t; i < DH * INCH / 4; i += 256) {
        int r = i >> 5, c = (i & 31) * 4;
        *(uint2*)&wsh[r * 132 + c] = ((const uint2*)W1h)[i];
    }
    __syncthreads();
    int w = t >> 6, lane = t & 63;
    int oc0 = w * 16;
    int rr = lane & 15, g = lane >> 4;
    f32x4 acc = {0.f, 0.f, 0.f, 0.f};
    #pragma unroll
    for (int ks = 0; ks < INCH / 16; ++ks) {
        f32x4 xv = *(const f32x4*)&xs[rr * 132 + ks * 16 + g * 4];
        half4 af = {(__fp16)xv.x, (__fp16)xv.y, (__fp16)xv.z, (__fp16)xv.w};
        half4 bf = *(const half4*)&wsh[(oc0 + rr) * 132 + ks * 16 + g * 4];
        acc = __builtin_amdgcn_mfma_f32_16x16x16f16(af, bf, acc, 0, 0, 0);
    }
    int oc = oc0 + rr;
    float bb = b1[oc];
    #pragma unroll
    for (int r = 0; r < 4; ++r) {
        int node = node0 + g * 4 + r;
        float v = eluf(acc[r] + bb);
        xout[(g * 4 + r) * 68 + oc] = v;
        if (node < N) X[(size_t)node * DH + oc] = v;
    }
    __syncthreads();
    float wsa = Ws0[lane];
    float wsb = Ws0[64 + lane];
    float wsc = Ws0[128 + lane];
    float wsd = Ws0[192 + lane];
    #pragma unroll
    for (int j = 0; j < 4; ++j) {
        int nl = w * 4 + j;
        int node = node0 + nl;
        float x = xout[nl * 68 + lane];
        float p0 = x * wsa, q0 = x * wsb, p1 = x * wsc, q1 = x * wsd;
        #pragma unroll
        for (int ofs = 32; ofs; ofs >>= 1) {
            p0 += __shfl_xor(p0, ofs);
            q0 += __shfl_xor(q0, ofs);
            p1 += __shfl_xor(p1, ofs);
            q1 += __shfl_xor(q1, ofs);
        }
        if (lane == 0 && node < N) {
            half4 pq = {(__fp16)p0, (__fp16)p1, (__fp16)q0, (__fp16)q1};
            *(half4*)(NDh + (size_t)node * 8) = pq;
        }
    }
}

// merged: blocks [0, Bdg) do degree pass; blocks [Bdg, Bdg+Blr) do XW GEMM
// XW layout: XWI[node*64 + m*8 + st*4 + j]  (quad-major, stalk-interleaved)
__global__ __launch_bounds__(256) void k_dglr(__fp16* __restrict__ NDh,
                                              const int* __restrict__ rowptr,
                                              const unsigned short* __restrict__ csr_dst,
                                              const float* __restrict__ X,
                                              const __fp16* __restrict__ Mlrh_l,
                                              __fp16* __restrict__ XWI,
                                              int Bdg, int N) {
    __shared__ float xs[16 * 68];            // padded
    __shared__ __fp16 mlh[DH * 68];
    if (blockIdx.x < Bdg) {
        int lane = threadIdx.x & 63;
        int widl = threadIdx.x >> 6;
        int nn = lane >> 4, sub = lane & 15;
        int node = blockIdx.x * 16 + widl * 4 + nn;
        if (node >= N) return;
        half4 pqu = *(const half4*)(NDh + (size_t)node * 8);
        float pu0 = (float)pqu[0], pu1 = (float)pqu[1];
        int pos = rowptr[node], end = rowptr[node + 1];
        float sx = 0.f, sy = 0.f;
        for (int i = pos + sub; i < end; i += 16) {
            int v = (int)__builtin_nontemporal_load(csr_dst + i);
            half4 pqv = *(const half4*)(NDh + (size_t)v * 8);
            float fx = ftanh(pu0 + (float)pqv[2]);
            float fy = ftanh(pu1 + (float)pqv[3]);
            sx += fx * fx;
            sy += fy * fy;
        }
        #pragma unroll
        for (int ofs = 8; ofs; ofs >>= 1) {
            sx += __shfl_xor(sx, ofs);
            sy += __shfl_xor(sy, ofs);
        }
        if (sub == 0) {
            float i0 = 1.f / (sx + 1.f), i1 = 1.f / (sy + 1.f);
            half4 gi = {(__fp16)sqrtf(i0), (__fp16)sqrtf(i1), (__fp16)(sx * i0), (__fp16)(sy * i1)};
            *(half4*)(NDh + (size_t)node * 8 + 4) = gi;
        }
        return;
    }
    int t = threadIdx.x;
    int node0 = (blockIdx.x - Bdg) * 16;
    for (int i = t; i < 16 * DH / 4; i += 256) {
        int r = i >> 4, c = (i & 15) * 4;
        int node = node0 + r;
        f32x4 v = (node < N) ? __builtin_nontemporal_load((const f32x4*)(X + (size_t)node * DH + c))
                             : (f32x4){0.f, 0.f, 0.f, 0.f};
        *(f32x4*)&xs[r * 68 + c] = v;
    }
    for (int i = t; i < DH * DH / 4; i += 256) {
        int r = i >> 4, c = (i & 15) * 4;
        *(uint2*)&mlh[r * 68 + c] = ((const uint2*)Mlrh_l)[i];
    }
    __syncthreads();
    int w = t >> 6, lane = t & 63;
    int oc0 = w * 16;
    int rr = lane & 15, g = lane >> 4;
    f32x4 acc = {0.f, 0.f, 0.f, 0.f};
    #pragma unroll
    for (int ks = 0; ks < DH / 16; ++ks) {
        f32x4 xv = *(const f32x4*)&xs[rr * 68 + ks * 16 + g * 4];
        half4 af = {(__fp16)xv.x, (__fp16)xv.y, (__fp16)xv.z, (__fp16)xv.w};
        half4 bf = *(const half4*)&mlh[(oc0 + rr) * 68 + ks * 16 + g * 4];
        acc = __builtin_amdgcn_mfma_f32_16x16x16f16(af, bf, acc, 0, 0, 0);
    }
    int oc = oc0 + rr;
    int sp = oc >> 5, c = oc & 31;
    int cidx = (c >> 2) * 8 + sp * 4 + (c & 3);
    #pragma unroll
    for (int r = 0; r < 4; ++r) {
        int node = node0 + g * 4 + r;
        if (node < N) XWI[(size_t)node * 64 + cidx] = (__fp16)acc[r];
    }
}

__global__ __launch_bounds__(256) void k_out(const float* __restrict__ X,
                                             const __fp16* __restrict__ W2h,
                                             const float* __restrict__ b2,
                                             float* __restrict__ out, int N) {
    __shared__ float xs[32 * 68];            // padded
    __shared__ __fp16 w2s[OUTC * 68];
    int t = threadIdx.x;
    int node0 = blockIdx.x * 32;
    for (int i = t; i < 32 * DH / 4; i += 256) {
        int r = i >> 4, c = (i & 15) * 4;
        int node = node0 + r;
        f32x4 v = (node < N) ? __builtin_nontemporal_load((const f32x4*)(X + (size_t)node * DH + c))
                             : (f32x4){0.f, 0.f, 0.f, 0.f};
        *(f32x4*)&xs[r * 68 + c] = v;
    }
    for (int i = t; i < OUTC * DH / 4; i += 256) {
        int r = i >> 4, c = (i & 15) * 4;
        *(uint2*)&w2s[r * 68 + c] = ((const uint2*)W2h)[i];
    }
    __syncthreads();
    int w = t >> 6, lane = t & 63;
    int nt = w >> 1;
    int oc0 = (w & 1) * 16;
    int rr = lane & 15, g = lane >> 4;
    f32x4 acc = {0.f, 0.f, 0.f, 0.f};
    #pragma unroll
    for (int ks = 0; ks < DH / 16; ++ks) {
        f32x4 xv = *(const f32x4*)&xs[(nt * 16 + rr) * 68 + ks * 16 + g * 4];
        half4 af = {(__fp16)xv.x, (__fp16)xv.y, (__fp16)xv.z, (__fp16)xv.w};
        half4 bf = *(const half4*)&w2s[(oc0 + rr) * 68 + ks * 16 + g * 4];
        acc = __builtin_amdgcn_mfma_f32_16x16x16f16(af, bf, acc, 0, 0, 0);
    }
    int oc = oc0 + rr;
    float bb = b2[oc];
    #pragma unroll
    for (int r = 0; r < 4; ++r) {
        int node = node0 + nt * 16 + g * 4 + r;
        if (node < N) out[(size_t)node * OUTC + oc] = acc[r] + bb;
    }
}

// ---------------- spmm + finalize + next-layer P/Q ----------------
__global__ void k_spmm_fin_pq(const __fp16* __restrict__ XWI,
                              const __fp16* __restrict__ NDh, const int* __restrict__ rowptr,
                              const unsigned short* __restrict__ csr_dst,
                              const float* __restrict__ eps_l, const float* __restrict__ Wsn,
                              float* __restrict__ X, __fp16* __restrict__ NDhn, int N) {
    int wid = (blockIdx.x * blockDim.x + threadIdx.x) >> 6;
    int lane = threadIdx.x & 63;
    if (wid >= N) return;
    int q = lane >> 3;        // edge slot 0..7
    int m = lane & 7;         // channel quad within stalk
    half8 ndu = *(const half8*)(NDh + (size_t)wid * 8);
    float pu0 = (float)ndu[0], pu1 = (float)ndu[1];
    float qu0 = (float)ndu[2], qu1 = (float)ndu[3];
    float dinv0 = (float)ndu[4], dinv1 = (float)ndu[5];
    int pos = rowptr[wid], end = rowptr[wid + 1];

    float a0x = 0.f, a0y = 0.f, a0z = 0.f, a0w = 0.f;
    float a1x = 0.f, a1y = 0.f, a1z = 0.f, a1w = 0.f;

    for (int chunk = pos; chunk < end; chunk += 64) {
        int myidx = chunk + lane;
        int dmy = 0;
        unsigned wpkmy = 0;
        if (myidx < end) {
            dmy = (int)__builtin_nontemporal_load(csr_dst + myidx);
            half8 ndd = *(const half8*)(NDh + (size_t)dmy * 8);
            float prod0 = ftanh_pair(pu0 + (float)ndd[2], (float)ndd[0] + qu0);
            float prod1 = ftanh_pair(pu1 + (float)ndd[3], (float)ndd[1] + qu1);
            float w0 = -prod0 * dinv0 * (float)ndd[4];
            float w1 = -prod1 * dinv1 * (float)ndd[5];
            half2h wp = {(__fp16)w0, (__fp16)w1};
            __builtin_memcpy(&wpkmy, &wp, 4);
        }
        int lim = end - chunk; if (lim > 64) lim = 64;
        for (int b = 0; b < lim; b += 8) {
            int sl = b + q;
            int d        = __shfl(dmy, sl);
            unsigned wpk = __shfl((int)wpkmy, sl);   // 0 for sl >= row length
            half2h wp;
            __builtin_memcpy(&wp, &wpk, 4);
            float w0e = (float)wp.x, w1e = (float)wp.y;
            half8 g = *(const half8*)(XWI + (size_t)d * 64 + m * 8);
            a0x += w0e * (float)g[0]; a0y += w0e * (float)g[1];
            a0z += w0e * (float)g[2]; a0w += w0e * (float)g[3];
            a1x += w1e * (float)g[4]; a1y += w1e * (float)g[5];
            a1z += w1e * (float)g[6]; a1w += w1e * (float)g[7];
        }
    }
    #pragma unroll
    for (int ofs = 8; ofs <= 32; ofs <<= 1) {
        a0x += __shfl_xor(a0x, ofs); a0y += __shfl_xor(a0y, ofs);
        a0z += __shfl_xor(a0z, ofs); a0w += __shfl_xor(a0w, ofs);
        a1x += __shfl_xor(a1x, ofs); a1y += __shfl_xor(a1y, ofs);
        a1z += __shfl_xor(a1z, ofs); a1w += __shfl_xor(a1w, ofs);
    }
    if (q == 0) {
        float diag0 = (float)ndu[6];
        float diag1 = (float)ndu[7];
        half8 xw = *(const half8*)(XWI + (size_t)wid * 64 + m * 8);
        size_t b0 = (size_t)wid * DH + m * 4;
        size_t b1 = b0 + 32;
        float coeff0 = 1.f + ftanh(eps_l[0]);
        float coeff1 = 1.f + ftanh(eps_l[1]);
        f32x4 xo0 = __builtin_nontemporal_load((const f32x4*)(X + b0));
        f32x4 xo1 = __builtin_nontemporal_load((const f32x4*)(X + b1));
        f32x4 xn0, xn1;
        xn0.x = coeff0 * xo0.x - eluf(diag0 * (float)xw[0] + a0x);
        xn0.y = coeff0 * xo0.y - eluf(diag0 * (float)xw[1] + a0y);
        xn0.z = coeff0 * xo0.z - eluf(diag0 * (float)xw[2] + a0z);
        xn0.w = coeff0 * xo0.w - eluf(diag0 * (float)xw[3] + a0w);
        xn1.x = coeff1 * xo1.x - eluf(diag1 * (float)xw[4] + a1x);
        xn1.y = coeff1 * xo1.y - eluf(diag1 * (float)xw[5] + a1y);
        xn1.z = coeff1 * xo1.z - eluf(diag1 * (float)xw[6] + a1z);
        xn1.w = coeff1 * xo1.w - eluf(diag1 * (float)xw[7] + a1w);
        __builtin_nontemporal_store(xn0, (f32x4*)(X + b0));
        __builtin_nontemporal_store(xn1, (f32x4*)(X + b1));
        if (Wsn) {
            f32x4 wa0 = *(const f32x4*)(Wsn + m * 4);
            f32x4 wa1 = *(const f32x4*)(Wsn + 32 + m * 4);
            f32x4 wb0 = *(const f32x4*)(Wsn + 64 + m * 4);
            f32x4 wb1 = *(const f32x4*)(Wsn + 96 + m * 4);
            f32x4 wc0 = *(const f32x4*)(Wsn + 128 + m * 4);
            f32x4 wc1 = *(const f32x4*)(Wsn + 160 + m * 4);
            f32x4 wd0 = *(const f32x4*)(Wsn + 192 + m * 4);
            f32x4 wd1 = *(const f32x4*)(Wsn + 224 + m * 4);
            float p0 = xn0.x * wa0.x + xn0.y * wa0.y + xn0.z * wa0.z + xn0.w * wa0.w
                     + xn1.x * wa1.x + xn1.y * wa1.y + xn1.z * wa1.z + xn1.w * wa1.w;
            float q0 = xn0.x * wb0.x + xn0.y * wb0.y + xn0.z * wb0.z + xn0.w * wb0.w
                     + xn1.x * wb1.x + xn1.y * wb1.y + xn1.z * wb1.z + xn1.w * wb1.w;
            float p1 = xn0.x * wc0.x + xn0.y * wc0.y + xn0.z * wc0.z + xn0.w * wc0.w
                     + xn1.x * wc1.x + xn1.y * wc1.y + xn1.z * wc1.z + xn1.w * wc1.w;
            float q1 = xn0.x * wd0.x + xn0.y * wd0.y + xn0.z * wd0.z + xn0.w * wd0.w
                     + xn1.x * wd1.x + xn1.y * wd1.y + xn1.z * wd1.z + xn1.w * wd1.w;
            #pragma unroll
            for (int ofs = 1; ofs < 8; ofs <<= 1) {
                p0 += __shfl_xor(p0, ofs);
                q0 += __shfl_xor(q0, ofs);
                p1 += __shfl_xor(p1, ofs);
                q1 += __shfl_xor(q1, ofs);
            }
            if (m == 0) {
                half4 pq = {(__fp16)p0, (__fp16)p1, (__fp16)q0, (__fp16)q1};
                *(half4*)(NDhn + (size_t)wid * 8) = pq;
            }
        }
    }
}

extern "C" void kernel_launch(void* const* d_in, const int* in_sizes, int n_in,
                              void* d_out, int out_size, void* d_ws, size_t ws_size,
                              hipStream_t stream) {
    const float* xin    = (const float*)d_in[0];
    const int*   ei     = (const int*)d_in[1];
    const float* W1     = (const float*)d_in[2];
    const float* b1     = (const float*)d_in[3];
    const float* Wsheaf = (const float*)d_in[4];
    const float* Wleft  = (const float*)d_in[5];
    const float* Wright = (const float*)d_in[6];
    const float* eps    = (const float*)d_in[7];
    const float* W2     = (const float*)d_in[8];
    const float* b2     = (const float*)d_in[9];
    float* out = (float*)d_out;

    int N = in_sizes[0] / INCH;
    int E = in_sizes[1] / 2;
    const int* src = ei;
    const int* dst = ei + E;

    size_t off = 0;
    auto alloc = [&](size_t nbytes) {
        char* p = (char*)d_ws + off;
        off += (nbytes + 255) & ~(size_t)255;
        return p;
    };
    float*          X       = (float*)alloc((size_t)N * DH * 4);
    __fp16*         XWI     = (__fp16*)alloc((size_t)N * DH * 2);
    __fp16*         NDha    = (__fp16*)alloc((size_t)N * 16);
    __fp16*         NDhb    = (__fp16*)alloc((size_t)N * 16);
    int*            deg     = (int*)alloc((size_t)N * 4);
    int*            rowptr  = (int*)alloc(((size_t)N + 1) * 4);
    int*            cur     = (int*)alloc((size_t)N * 4);
    unsigned short* csr_dst = (unsigned short*)alloc((size_t)E * 2);
    int*            bsum    = (int*)alloc(4096);
    __fp16*         W1h     = (__fp16*)alloc((size_t)DH * INCH * 2);
    __fp16*         W2h     = (__fp16*)alloc((size_t)OUTC * DH * 2);
    __fp16*         Mlrh    = (__fp16*)alloc((size_t)LAYERS * DH * DH * 2);

    int B = (N + 1023) / 1024;

    int prep_total = DH * INCH + OUTC * DH + LAYERS * DH * DH;
    int Bp = (prep_total + 255) / 256;
    int Bh = (E + 255) / 256;
    hipMemsetAsync(deg, 0, (size_t)N * sizeof(int), stream);
    k_prep_hist<<<Bp + Bh, 256, 0, stream>>>(W1, W2, Wleft, Wright, W1h, W2h, Mlrh,
                                             src, deg, Bp, E);
    k_bsum<<<B, 256, 0, stream>>>(deg, bsum, N);
    k_scan_small<<<1, 64, 0, stream>>>(bsum, B);
    k_scan_final<<<B, 256, 0, stream>>>(deg, bsum, rowptr, cur, N);

    int Bs = (E + 255) / 256;
    int Bm = (N + 15) / 16;
    k_scatter_mlp1<<<Bs + Bm, 256, 0, stream>>>(src, dst, cur, csr_dst, E,
                                                xin, W1h, b1, Wsheaf, X, NDha, Bs, N);

    __fp16* NDcur = NDha;
    __fp16* NDnext = NDhb;
    int Bdg = (N + 15) / 16;
    int Blr = (N + 15) / 16;
    for (int l = 0; l < LAYERS; ++l) {
        k_dglr<<<Bdg + Blr, 256, 0, stream>>>(NDcur, rowptr, csr_dst, X,
                                              Mlrh + (size_t)l * DH * DH, XWI, Bdg, N);
        const float* Wsn = (l + 1 < LAYERS) ? (Wsheaf + (l + 1) * 2 * INCH) : nullptr;
        k_spmm_fin_pq<<<(N + 3) / 4, 256, 0, stream>>>(XWI, NDcur, rowptr, csr_dst,
                                                       eps + l * 2, Wsn, X, NDnext, N);
        __fp16* tmp = NDcur; NDcur = NDnext; NDnext = tmp;
    }

    k_out<<<(N + 31) / 32, 256, 0, stream>>>(X, W2h, b2, out, N);
}